// Round 1
// baseline (372.457 us; speedup 1.0000x reference)
//
#include <hip/hip_runtime.h>
#include <hip/hip_bf16.h>
#include <math.h>

typedef __bf16 bf16x8 __attribute__((ext_vector_type(8)));
typedef float f32x4 __attribute__((ext_vector_type(4)));
typedef unsigned short u16;

#define DEV __device__ __forceinline__

static constexpr int Bc = 2, Sc = 2048, Dc = 1024, Hc = 16, DFFc = 4096, DKc = 64;
static constexpr int Mc = Bc * Sc; // 4096 rows

DEV u16 f32_to_bf16(float x) {
    unsigned u = __builtin_bit_cast(unsigned, x);
    u += 0x7FFFu + ((u >> 16) & 1u);   // round-to-nearest-even
    return (u16)(u >> 16);
}

DEV float block_reduce_sum(float v) {
    __shared__ float part[4];
    int lane = threadIdx.x & 63, w = threadIdx.x >> 6;
    #pragma unroll
    for (int m = 1; m < 64; m <<= 1) v += __shfl_xor(v, m);
    __syncthreads();                    // protect reuse across calls
    if (lane == 0) part[w] = v;
    __syncthreads();
    return part[0] + part[1] + part[2] + part[3];
}

// LayerNorm over last dim D=1024: f32 in -> bf16 out. Unbiased std, /(std+eps),
// scalar alpha/beta (1-element arrays). One 256-thread block per row.
__global__ __launch_bounds__(256)
void ln_kernel(const float* __restrict__ x, u16* __restrict__ y,
               const float* __restrict__ alpha, const float* __restrict__ beta) {
    long row = blockIdx.x;
    const float4 v = reinterpret_cast<const float4*>(x + row * Dc)[threadIdx.x];
    float s = v.x + v.y + v.z + v.w;
    s = block_reduce_sum(s);
    float mean = s * (1.0f / Dc);
    float d0 = v.x - mean, d1 = v.y - mean, d2 = v.z - mean, d3 = v.w - mean;
    float ss = d0*d0 + d1*d1 + d2*d2 + d3*d3;
    ss = block_reduce_sum(ss);
    float stdv = sqrtf(ss / (float)(Dc - 1));
    float sc = alpha[0] / (stdv + 1e-6f);
    float bi = beta[0];
    ushort4 o;
    o.x = f32_to_bf16(d0 * sc + bi);
    o.y = f32_to_bf16(d1 * sc + bi);
    o.z = f32_to_bf16(d2 * sc + bi);
    o.w = f32_to_bf16(d3 * sc + bi);
    reinterpret_cast<ushort4*>(y + row * Dc)[threadIdx.x] = o;
}

// f32 W[K][N] -> bf16 WT[N][K]  (tiled 32x32 via LDS)
__global__ void transpose_conv_kernel(const float* __restrict__ in, u16* __restrict__ out,
                                      int K, int N) {
    __shared__ float tile[32][33];
    int k0 = blockIdx.y * 32, n0 = blockIdx.x * 32;
    int tx = threadIdx.x, ty = threadIdx.y; // (32,8)
    #pragma unroll
    for (int i = 0; i < 4; i++)
        tile[ty + i*8][tx] = in[(long)(k0 + ty + i*8) * N + n0 + tx];
    __syncthreads();
    #pragma unroll
    for (int i = 0; i < 4; i++)
        out[(long)(n0 + ty + i*8) * K + k0 + tx] = f32_to_bf16(tile[tx][ty + i*8]);
}

// ---------------- bf16 GEMM: C = A[M,K] @ B  with B given as BT[N][K] ----------------
// 128x128 tile, BK=64, 256 threads (4 waves in 2x2), 16x16x32 MFMA, f32 accum.
enum { EPI_QK = 0, EPI_VT = 1, EPI_RELU = 2, EPI_RES = 3 };

template<int EPI>
__global__ __launch_bounds__(256)
void gemm_kernel(const u16* __restrict__ A, const u16* __restrict__ BT,
                 const float* __restrict__ bias, void* __restrict__ outp,
                 const float* __restrict__ res, int M, int N, int K) {
    constexpr int BM = 128, BN = 128, BK = 64, LDT = BK + 8; // pad 8 bf16 = 16B
    __shared__ u16 As[BM * LDT];
    __shared__ u16 Bs[BN * LDT];
    const int tid = threadIdx.x;
    const int wave = tid >> 6, lane = tid & 63;
    const int wr = wave >> 1, wc = wave & 1;
    const int lr = lane & 15, lg = lane >> 4;
    const int m0 = blockIdx.y * BM, n0 = blockIdx.x * BN;

    f32x4 acc[4][4] = {};

    for (int kt = 0; kt < K; kt += BK) {
        #pragma unroll
        for (int i = 0; i < 4; i++) {
            int cl = tid + i * 256;           // 1024 chunks of 16B
            int r = cl >> 3, c = (cl & 7) * 8;
            *reinterpret_cast<uint4*>(&As[r * LDT + c]) =
                *reinterpret_cast<const uint4*>(&A[(long)(m0 + r) * K + kt + c]);
            *reinterpret_cast<uint4*>(&Bs[r * LDT + c]) =
                *reinterpret_cast<const uint4*>(&BT[(long)(n0 + r) * K + kt + c]);
        }
        __syncthreads();
        #pragma unroll
        for (int ks = 0; ks < BK; ks += 32) {
            bf16x8 a[4], b[4];
            #pragma unroll
            for (int i = 0; i < 4; i++)
                a[i] = *reinterpret_cast<const bf16x8*>(&As[(wr*64 + i*16 + lr) * LDT + ks + lg*8]);
            #pragma unroll
            for (int j = 0; j < 4; j++)
                b[j] = *reinterpret_cast<const bf16x8*>(&Bs[(wc*64 + j*16 + lr) * LDT + ks + lg*8]);
            #pragma unroll
            for (int i = 0; i < 4; i++)
                #pragma unroll
                for (int j = 0; j < 4; j++)
                    acc[i][j] = __builtin_amdgcn_mfma_f32_16x16x32_bf16(a[i], b[j], acc[i][j], 0, 0, 0);
        }
        __syncthreads();
    }

    #pragma unroll
    for (int i = 0; i < 4; i++) {
        #pragma unroll
        for (int j = 0; j < 4; j++) {
            const int col = n0 + wc*64 + j*16 + lr;
            const float bv = bias[col];
            #pragma unroll
            for (int rg = 0; rg < 4; rg++) {
                const int row = m0 + wr*64 + i*16 + lg*4 + rg;
                float val = acc[i][j][rg] + bv;
                if constexpr (EPI == EPI_QK) {
                    int bb = row >> 11, s = row & (Sc - 1);
                    int hh = col >> 6, dk = col & 63;
                    ((u16*)outp)[(((long)(bb * Hc + hh) * Sc + s) << 6) + dk] = f32_to_bf16(val);
                } else if constexpr (EPI == EPI_VT) {
                    int bb = row >> 11, s = row & (Sc - 1);
                    int hh = col >> 6, dk = col & 63;
                    ((u16*)outp)[((long)(bb * Hc + hh) * DKc + dk) * Sc + s] = f32_to_bf16(val);
                } else if constexpr (EPI == EPI_RELU) {
                    ((u16*)outp)[(long)row * N + col] = f32_to_bf16(fmaxf(val, 0.0f));
                } else { // EPI_RES: out(f32) = res + acc + bias
                    long idx = (long)row * N + col;
                    ((float*)outp)[idx] = res[idx] + val;
                }
            }
        }
    }
}

// ---------------- flash attention ----------------
// grid (S/64, B*H), 256 threads (4 waves). Each wave owns 16 q-rows.
// Q,K: [B,H,S,64] bf16.  VT: [B,H,64,S] bf16.  out: [B,S,D] bf16.
__global__ __launch_bounds__(256)
void attn_kernel(const u16* __restrict__ Qg, const u16* __restrict__ Kg,
                 const u16* __restrict__ VTg, const int* __restrict__ mask,
                 u16* __restrict__ Aout) {
    constexpr int LDT = 72;
    __shared__ u16 Qs[64 * LDT], Ks[64 * LDT], VTs[64 * LDT], Ps[64 * LDT];
    __shared__ float mbias[64];

    const int tid = threadIdx.x;
    const int wave = tid >> 6, lane = tid & 63;
    const int lr = lane & 15, lg = lane >> 4;
    const int bh = blockIdx.y;
    const int b = bh >> 4, hh = bh & 15;
    const int q0 = blockIdx.x * 64;
    const long base = (long)bh * Sc * DKc; // Q/K: [bh][s][dk]; VT: [bh][dk][s] (same size)

    // stage Q tile (64x64)
    #pragma unroll
    for (int i = 0; i < 2; i++) {
        int cl = tid + i * 256;
        int r = cl >> 3, c = (cl & 7) * 8;
        *reinterpret_cast<uint4*>(&Qs[r * LDT + c]) =
            *reinterpret_cast<const uint4*>(&Qg[base + (long)(q0 + r) * DKc + c]);
    }

    f32x4 accO[4] = {};
    float mrun[4], lrun[4];
    #pragma unroll
    for (int r = 0; r < 4; r++) { mrun[r] = -3.0e38f; lrun[r] = 0.f; }
    const float scale = 0.125f; // 1/sqrt(64)

    for (int kt = 0; kt < Sc; kt += 64) {
        #pragma unroll
        for (int i = 0; i < 2; i++) {
            int cl = tid + i * 256;
            int r = cl >> 3, c = (cl & 7) * 8;
            *reinterpret_cast<uint4*>(&Ks[r * LDT + c]) =
                *reinterpret_cast<const uint4*>(&Kg[base + (long)(kt + r) * DKc + c]);
            *reinterpret_cast<uint4*>(&VTs[r * LDT + c]) =
                *reinterpret_cast<const uint4*>(&VTg[base + (long)r * Sc + kt + c]);
        }
        if (tid < 64) mbias[tid] = mask[b * Sc + kt + tid] ? 0.f : -1e9f;
        __syncthreads();

        // S-tile = Q K^T : wave's 16 rows x 64 cols
        f32x4 st[4] = {};
        #pragma unroll
        for (int ks = 0; ks < 64; ks += 32) {
            bf16x8 aq = *reinterpret_cast<const bf16x8*>(&Qs[(wave*16 + lr) * LDT + ks + lg*8]);
            #pragma unroll
            for (int j = 0; j < 4; j++) {
                bf16x8 bk = *reinterpret_cast<const bf16x8*>(&Ks[(j*16 + lr) * LDT + ks + lg*8]);
                st[j] = __builtin_amdgcn_mfma_f32_16x16x32_bf16(aq, bk, st[j], 0, 0, 0);
            }
        }
        // scale + mask, per-row max (rows live on 16-lane groups: row=(lane>>4)*4+rg)
        float sv[4][4], pm[4];
        #pragma unroll
        for (int rg = 0; rg < 4; rg++) pm[rg] = -3.0e38f;
        #pragma unroll
        for (int j = 0; j < 4; j++) {
            float mb = mbias[j*16 + lr];
            #pragma unroll
            for (int rg = 0; rg < 4; rg++) {
                float v = st[j][rg] * scale + mb;
                sv[j][rg] = v;
                pm[rg] = fmaxf(pm[rg], v);
            }
        }
        #pragma unroll
        for (int m = 1; m < 16; m <<= 1)
            #pragma unroll
            for (int rg = 0; rg < 4; rg++)
                pm[rg] = fmaxf(pm[rg], __shfl_xor(pm[rg], m));
        // online softmax update
        float corr[4], rsum[4];
        #pragma unroll
        for (int rg = 0; rg < 4; rg++) {
            float mnew = fmaxf(mrun[rg], pm[rg]);
            corr[rg] = __expf(mrun[rg] - mnew);
            mrun[rg] = mnew;
            float s = 0.f;
            #pragma unroll
            for (int j = 0; j < 4; j++) {
                float pv = __expf(sv[j][rg] - mnew);
                sv[j][rg] = pv;
                s += pv;
            }
            rsum[rg] = s;
        }
        #pragma unroll
        for (int m = 1; m < 16; m <<= 1)
            #pragma unroll
            for (int rg = 0; rg < 4; rg++) rsum[rg] += __shfl_xor(rsum[rg], m);
        #pragma unroll
        for (int rg = 0; rg < 4; rg++) {
            lrun[rg] = lrun[rg] * corr[rg] + rsum[rg];
            #pragma unroll
            for (int j = 0; j < 4; j++) accO[j][rg] *= corr[rg];
        }
        // P -> LDS (bf16). Wave-local rows: no barrier needed (same-wave DS ordering).
        #pragma unroll
        for (int j = 0; j < 4; j++)
            #pragma unroll
            for (int rg = 0; rg < 4; rg++)
                Ps[(wave*16 + lg*4 + rg) * LDT + j*16 + lr] = f32_to_bf16(sv[j][rg]);
        // PV: out += P @ V  (B-operand from VT tile: rows=dk, contiguous k)
        #pragma unroll
        for (int ks = 0; ks < 64; ks += 32) {
            bf16x8 ap = *reinterpret_cast<const bf16x8*>(&Ps[(wave*16 + lr) * LDT + ks + lg*8]);
            #pragma unroll
            for (int j = 0; j < 4; j++) {
                bf16x8 bv = *reinterpret_cast<const bf16x8*>(&VTs[(j*16 + lr) * LDT + ks + lg*8]);
                accO[j] = __builtin_amdgcn_mfma_f32_16x16x32_bf16(ap, bv, accO[j], 0, 0, 0);
            }
        }
        __syncthreads();
    }

    // write A[b, s, h*64+dk] bf16
    #pragma unroll
    for (int j = 0; j < 4; j++) {
        #pragma unroll
        for (int rg = 0; rg < 4; rg++) {
            int srow = q0 + wave*16 + lg*4 + rg;
            float val = accO[j][rg] / lrun[rg];
            Aout[((long)(b * Sc + srow)) * Dc + hh*64 + j*16 + lr] = f32_to_bf16(val);
        }
    }
}

extern "C" void kernel_launch(void* const* d_in, const int* in_sizes, int n_in,
                              void* d_out, int out_size, void* d_ws, size_t ws_size,
                              hipStream_t stream) {
    (void)in_sizes; (void)n_in; (void)out_size; (void)ws_size;
    const float* xb = (const float*)d_in[0];
    const int*  mask = (const int*)d_in[1];
    const float* Wq = (const float*)d_in[2];
    const float* bq = (const float*)d_in[3];
    const float* Wk = (const float*)d_in[4];
    const float* bk = (const float*)d_in[5];
    const float* Wv = (const float*)d_in[6];
    const float* bv = (const float*)d_in[7];
    const float* Wo = (const float*)d_in[8];
    const float* bo = (const float*)d_in[9];
    const float* W1 = (const float*)d_in[10];
    const float* b1 = (const float*)d_in[11];
    const float* W2 = (const float*)d_in[12];
    const float* b2 = (const float*)d_in[13];
    const float* a1 = (const float*)d_in[14];
    const float* o1 = (const float*)d_in[15];
    const float* a2 = (const float*)d_in[16];
    const float* o2 = (const float*)d_in[17];
    float* out = (float*)d_out;

    char* p = (char*)d_ws;
    auto alloc = [&](size_t bytes) { char* r = p; p += (bytes + 255) & ~(size_t)255; return r; };
    u16* xln = (u16*)alloc((size_t)Mc * Dc * 2);
    u16* WTq = (u16*)alloc((size_t)Dc * Dc * 2);
    u16* WTk = (u16*)alloc((size_t)Dc * Dc * 2);
    u16* WTv = (u16*)alloc((size_t)Dc * Dc * 2);
    u16* WTo = (u16*)alloc((size_t)Dc * Dc * 2);
    u16* WT1 = (u16*)alloc((size_t)Dc * DFFc * 2);
    u16* WT2 = (u16*)alloc((size_t)DFFc * Dc * 2);
    u16* Qb  = (u16*)alloc((size_t)Mc * Dc * 2);
    u16* Kb  = (u16*)alloc((size_t)Mc * Dc * 2);
    u16* VTb = (u16*)alloc((size_t)Mc * Dc * 2);
    u16* Aat = (u16*)alloc((size_t)Mc * Dc * 2);
    float* hbuf = (float*)alloc((size_t)Mc * Dc * 4);
    u16* zb  = (u16*)alloc((size_t)Mc * Dc * 2);
    u16* ffh = (u16*)alloc((size_t)Mc * DFFc * 2);

    dim3 blkT(32, 8);
    transpose_conv_kernel<<<dim3(Dc/32,   Dc/32),   blkT, 0, stream>>>(Wq, WTq, Dc, Dc);
    transpose_conv_kernel<<<dim3(Dc/32,   Dc/32),   blkT, 0, stream>>>(Wk, WTk, Dc, Dc);
    transpose_conv_kernel<<<dim3(Dc/32,   Dc/32),   blkT, 0, stream>>>(Wv, WTv, Dc, Dc);
    transpose_conv_kernel<<<dim3(Dc/32,   Dc/32),   blkT, 0, stream>>>(Wo, WTo, Dc, Dc);
    transpose_conv_kernel<<<dim3(DFFc/32, Dc/32),   blkT, 0, stream>>>(W1, WT1, Dc, DFFc);
    transpose_conv_kernel<<<dim3(Dc/32,   DFFc/32), blkT, 0, stream>>>(W2, WT2, DFFc, Dc);

    ln_kernel<<<Mc, 256, 0, stream>>>(xb, xln, a1, o1);

    gemm_kernel<EPI_QK><<<dim3(Dc/128, Mc/128), 256, 0, stream>>>(xln, WTq, bq, Qb,  nullptr, Mc, Dc, Dc);
    gemm_kernel<EPI_QK><<<dim3(Dc/128, Mc/128), 256, 0, stream>>>(xln, WTk, bk, Kb,  nullptr, Mc, Dc, Dc);
    gemm_kernel<EPI_VT><<<dim3(Dc/128, Mc/128), 256, 0, stream>>>(xln, WTv, bv, VTb, nullptr, Mc, Dc, Dc);

    attn_kernel<<<dim3(Sc/64, Bc*Hc), 256, 0, stream>>>(Qb, Kb, VTb, mask, Aat);

    gemm_kernel<EPI_RES><<<dim3(Dc/128, Mc/128), 256, 0, stream>>>(Aat, WTo, bo, hbuf, xb, Mc, Dc, Dc);

    ln_kernel<<<Mc, 256, 0, stream>>>(hbuf, zb, a2, o2);

    gemm_kernel<EPI_RELU><<<dim3(DFFc/128, Mc/128), 256, 0, stream>>>(zb,  WT1, b1, ffh, nullptr, Mc, DFFc, Dc);
    gemm_kernel<EPI_RES><<<dim3(Dc/128,  Mc/128), 256, 0, stream>>>(ffh, WT2, b2, out, hbuf, Mc, Dc, DFFc);
}

// Round 2
// 329.198 us; speedup vs baseline: 1.1314x; 1.1314x over previous
//
#include <hip/hip_runtime.h>
#include <hip/hip_bf16.h>
#include <math.h>

typedef __bf16 bf16x8 __attribute__((ext_vector_type(8)));
typedef float f32x4 __attribute__((ext_vector_type(4)));
typedef unsigned short u16;

#define DEV __device__ __forceinline__

static constexpr int Bc = 2, Sc = 2048, Dc = 1024, Hc = 16, DFFc = 4096, DKc = 64;
static constexpr int Mc = Bc * Sc; // 4096 rows
static constexpr float QSCALE = 0.125f * 1.4426950408889634f; // fold 1/sqrt(dk) * log2(e) into Q

DEV u16 f32_to_bf16(float x) {
    unsigned u = __builtin_bit_cast(unsigned, x);
    u += 0x7FFFu + ((u >> 16) & 1u);   // round-to-nearest-even
    return (u16)(u >> 16);
}

DEV float exp2_fast(float x) {       // v_exp_f32 computes 2^x natively
    float r;
    asm("v_exp_f32 %0, %1" : "=v"(r) : "v"(x));
    return r;
}

// async global->LDS, 16B per lane; LDS dest = wave-uniform base + lane*16
DEV void gload_lds16(const u16* g, u16* l) {
    __builtin_amdgcn_global_load_lds(
        (const __attribute__((address_space(1))) void*)g,
        (__attribute__((address_space(3))) void*)l, 16, 0, 0);
}

DEV float block_reduce_sum(float v) {
    __shared__ float part[4];
    int lane = threadIdx.x & 63, w = threadIdx.x >> 6;
    #pragma unroll
    for (int m = 1; m < 64; m <<= 1) v += __shfl_xor(v, m);
    __syncthreads();
    if (lane == 0) part[w] = v;
    __syncthreads();
    return part[0] + part[1] + part[2] + part[3];
}

// LayerNorm over last dim D=1024: f32 in -> bf16 out.
__global__ __launch_bounds__(256)
void ln_kernel(const float* __restrict__ x, u16* __restrict__ y,
               const float* __restrict__ alpha, const float* __restrict__ beta) {
    long row = blockIdx.x;
    const float4 v = reinterpret_cast<const float4*>(x + row * Dc)[threadIdx.x];
    float s = v.x + v.y + v.z + v.w;
    s = block_reduce_sum(s);
    float mean = s * (1.0f / Dc);
    float d0 = v.x - mean, d1 = v.y - mean, d2 = v.z - mean, d3 = v.w - mean;
    float ss = d0*d0 + d1*d1 + d2*d2 + d3*d3;
    ss = block_reduce_sum(ss);
    float stdv = sqrtf(ss / (float)(Dc - 1));
    float sc = alpha[0] / (stdv + 1e-6f);
    float bi = beta[0];
    ushort4 o;
    o.x = f32_to_bf16(d0 * sc + bi);
    o.y = f32_to_bf16(d1 * sc + bi);
    o.z = f32_to_bf16(d2 * sc + bi);
    o.w = f32_to_bf16(d3 * sc + bi);
    reinterpret_cast<ushort4*>(y + row * Dc)[threadIdx.x] = o;
}

// f32 W[K][N] -> bf16 WT[N][K]
__global__ void transpose_conv_kernel(const float* __restrict__ in, u16* __restrict__ out,
                                      int K, int N) {
    __shared__ float tile[32][33];
    int k0 = blockIdx.y * 32, n0 = blockIdx.x * 32;
    int tx = threadIdx.x, ty = threadIdx.y; // (32,8)
    #pragma unroll
    for (int i = 0; i < 4; i++)
        tile[ty + i*8][tx] = in[(long)(k0 + ty + i*8) * N + n0 + tx];
    __syncthreads();
    #pragma unroll
    for (int i = 0; i < 4; i++)
        out[(long)(n0 + ty + i*8) * K + k0 + tx] = f32_to_bf16(tile[tx][ty + i*8]);
}

// ---------------- bf16 GEMM (m97 structure): C = A[M,K] @ B with B as BT[N][K] ----------------
// global_load_lds width-16 staging into LINEAR LDS, 2 barriers per K-step.
enum { EPI_QKV = 0, EPI_RELU = 1, EPI_RES = 2 };

template<int EPI, int BM, int BN>
__global__ __launch_bounds__(256, 3)
void gemm_kernel(const u16* __restrict__ A, const u16* __restrict__ BT,
                 const float* __restrict__ b0, const float* __restrict__ b1,
                 const float* __restrict__ b2, void* __restrict__ outp,
                 const float* __restrict__ res, int M, int N, int K) {
    constexpr int BK = 64, RI = BM / 32, RJ = BN / 32;
    __shared__ u16 As[BM * BK];
    __shared__ u16 Bs[BN * BK];
    const int tid = threadIdx.x;
    const int wave = tid >> 6, lane = tid & 63;
    const int wr = wave >> 1, wc = wave & 1;
    const int lr = lane & 15, lg = lane >> 4;
    const int m0 = blockIdx.y * BM, n0 = blockIdx.x * BN;
    const int z = blockIdx.z;
    const u16* Bz = BT + (size_t)z * N * K;
    const int srow = lane >> 3, scol = (lane & 7) * 8; // 8 rows x 64 cols per 1KB chunk

    f32x4 acc[RI][RJ] = {};

    const u16* ap[RI];
    const u16* bp[RJ];
    #pragma unroll
    for (int i = 0; i < RI; i++) ap[i] = A  + (size_t)(m0 + (wave*RI + i)*8 + srow) * K + scol;
    #pragma unroll
    for (int j = 0; j < RJ; j++) bp[j] = Bz + (size_t)(n0 + (wave*RJ + j)*8 + srow) * K + scol;

    for (int kt = 0; kt < K; kt += BK) {
        #pragma unroll
        for (int i = 0; i < RI; i++) gload_lds16(ap[i] + kt, &As[(wave*RI + i) * 512]);
        #pragma unroll
        for (int j = 0; j < RJ; j++) gload_lds16(bp[j] + kt, &Bs[(wave*RJ + j) * 512]);
        __syncthreads();   // drains vmcnt -> LDS data visible
        #pragma unroll
        for (int ks = 0; ks < BK; ks += 32) {
            bf16x8 a[RI], b[RJ];
            #pragma unroll
            for (int i = 0; i < RI; i++)
                a[i] = *reinterpret_cast<const bf16x8*>(&As[(wr*(BM/2) + i*16 + lr) * BK + ks + lg*8]);
            #pragma unroll
            for (int j = 0; j < RJ; j++)
                b[j] = *reinterpret_cast<const bf16x8*>(&Bs[(wc*(BN/2) + j*16 + lr) * BK + ks + lg*8]);
            #pragma unroll
            for (int i = 0; i < RI; i++)
                #pragma unroll
                for (int j = 0; j < RJ; j++)
                    acc[i][j] = __builtin_amdgcn_mfma_f32_16x16x32_bf16(a[i], b[j], acc[i][j], 0, 0, 0);
        }
        __syncthreads();   // all reads done before next stage overwrites
    }

    const float* bias = (EPI == EPI_QKV) ? (z == 0 ? b0 : z == 1 ? b1 : b2) : b0;
    #pragma unroll
    for (int i = 0; i < RI; i++) {
        #pragma unroll
        for (int j = 0; j < RJ; j++) {
            const int col = n0 + wc*(BN/2) + j*16 + lr;
            const float bv = bias[col];
            #pragma unroll
            for (int rg = 0; rg < 4; rg++) {
                const int row = m0 + wr*(BM/2) + i*16 + lg*4 + rg;
                float val = acc[i][j][rg] + bv;
                if constexpr (EPI == EPI_QKV) {
                    int bb = row >> 11, s = row & (Sc - 1);
                    int hh = col >> 6, dk = col & 63;
                    u16* o = (u16*)outp + (size_t)z * Mc * Dc;
                    if (z == 2)  // V transposed: [B,H,DK,S]
                        o[((size_t)(bb * Hc + hh) * DKc + dk) * Sc + s] = f32_to_bf16(val);
                    else         // Q (pre-scaled) / K: [B,H,S,DK]
                        o[(((size_t)(bb * Hc + hh) * Sc + s) << 6) + dk] =
                            f32_to_bf16(z == 0 ? val * QSCALE : val);
                } else if constexpr (EPI == EPI_RELU) {
                    ((u16*)outp)[(size_t)row * N + col] = f32_to_bf16(fmaxf(val, 0.0f));
                } else { // EPI_RES: out(f32) = res + acc + bias
                    size_t idx = (size_t)row * N + col;
                    ((float*)outp)[idx] = res[idx] + val;
                }
            }
        }
    }
}

// ---------------- flash attention ----------------
// grid (S/128, B*H), 512 threads (8 waves). Each wave owns 16 q-rows, Q in regs.
// Q,K: [B,H,S,64] bf16 (Q pre-scaled by QSCALE). VT: [B,H,64,S]. out: [B,S,D] bf16.
// Scores are in log2 domain -> exp2. Double-buffered K/V, 1 barrier/tile.
__global__ __launch_bounds__(512, 4)
void attn_kernel(const u16* __restrict__ Qg, const u16* __restrict__ Kg,
                 const u16* __restrict__ VTg, const int* __restrict__ mask,
                 u16* __restrict__ Aout) {
    constexpr int LDT = 72, KVB = 64, NT = Sc / KVB;
    __shared__ u16 Ks[2][KVB * LDT];
    __shared__ u16 VTs[2][KVB * LDT];
    __shared__ u16 Ps[8][16 * LDT];
    __shared__ float mb_full[Sc];

    const int tid = threadIdx.x;
    const int wave = tid >> 6, lane = tid & 63;
    const int lr = lane & 15, lg = lane >> 4;
    const int bh = blockIdx.y;
    const int b = bh >> 4, hh = bh & 15;
    const int q0 = blockIdx.x * 128;
    const long base = (long)bh * Sc * DKc;

    // mask bias for the whole row, once per block
    for (int i = tid; i < Sc; i += 512)
        mb_full[i] = mask[b * Sc + i] ? 0.f : -1e9f;

    // Q fragment in registers (A-operand: row = lane&15, k = (lane>>4)*8 + e)
    const u16* qrow = Qg + base + (long)(q0 + wave * 16 + lr) * DKc;
    bf16x8 qf[2];
    qf[0] = *reinterpret_cast<const bf16x8*>(qrow + lg * 8);
    qf[1] = *reinterpret_cast<const bf16x8*>(qrow + 32 + lg * 8);

    // reg-staged K/V: each of 512 threads carries one uint4 of K and of V
    const int srow = tid >> 3, scol = (tid & 7) * 8;
    uint4 kreg, vreg;
    auto load_kv = [&](int kt) {
        kreg = *reinterpret_cast<const uint4*>(&Kg [base + (long)(kt + srow) * DKc + scol]);
        vreg = *reinterpret_cast<const uint4*>(&VTg[base + (long)srow * Sc + kt + scol]);
    };
    auto write_kv = [&](int bufi) {
        *reinterpret_cast<uint4*>(&Ks [bufi][srow * LDT + scol]) = kreg;
        *reinterpret_cast<uint4*>(&VTs[bufi][srow * LDT + scol]) = vreg;
    };

    load_kv(0);
    write_kv(0);
    __syncthreads();

    f32x4 accO[4] = {};
    float mrun[4], lrun[4];
    #pragma unroll
    for (int r = 0; r < 4; r++) { mrun[r] = -3.0e38f; lrun[r] = 0.f; }

    for (int t = 0; t < NT; t++) {
        const int cur = t & 1;
        if (t + 1 < NT) load_kv((t + 1) * KVB);   // issue early (T14)

        // S-tile = (Q*c) K^T in log2 domain
        f32x4 st[4] = {};
        #pragma unroll
        for (int ksi = 0; ksi < 2; ksi++) {
            #pragma unroll
            for (int j = 0; j < 4; j++) {
                bf16x8 bk = *reinterpret_cast<const bf16x8*>(&Ks[cur][(j*16 + lr) * LDT + ksi*32 + lg*8]);
                st[j] = __builtin_amdgcn_mfma_f32_16x16x32_bf16(qf[ksi], bk, st[j], 0, 0, 0);
            }
        }
        // mask add + row max (row = lg*4+rg, cols on 16-lane groups)
        float sv[4][4], pm[4];
        #pragma unroll
        for (int rg = 0; rg < 4; rg++) pm[rg] = -3.0e38f;
        #pragma unroll
        for (int j = 0; j < 4; j++) {
            float mb = mb_full[t * KVB + j*16 + lr];
            #pragma unroll
            for (int rg = 0; rg < 4; rg++) {
                float v = st[j][rg] + mb;
                sv[j][rg] = v;
                pm[rg] = fmaxf(pm[rg], v);
            }
        }
        #pragma unroll
        for (int m = 1; m < 16; m <<= 1)
            #pragma unroll
            for (int rg = 0; rg < 4; rg++)
                pm[rg] = fmaxf(pm[rg], __shfl_xor(pm[rg], m));

        // defer-rescale (T13): only rescale when max grew by > 8 nats (11.54 in log2)
        float needs = pm[0] - mrun[0];
        #pragma unroll
        for (int rg = 1; rg < 4; rg++) needs = fmaxf(needs, pm[rg] - mrun[rg]);
        if (__any(needs > 11.54f)) {
            #pragma unroll
            for (int rg = 0; rg < 4; rg++) {
                float mnew = fmaxf(mrun[rg], pm[rg]);
                float corr = exp2_fast(mrun[rg] - mnew);
                mrun[rg] = mnew;
                lrun[rg] *= corr;
                #pragma unroll
                for (int j = 0; j < 4; j++) accO[j][rg] *= corr;
            }
        }
        float rsum[4] = {0.f, 0.f, 0.f, 0.f};
        #pragma unroll
        for (int j = 0; j < 4; j++)
            #pragma unroll
            for (int rg = 0; rg < 4; rg++) {
                float p = exp2_fast(sv[j][rg] - mrun[rg]);
                sv[j][rg] = p;
                rsum[rg] += p;
            }
        #pragma unroll
        for (int m = 1; m < 16; m <<= 1)
            #pragma unroll
            for (int rg = 0; rg < 4; rg++) rsum[rg] += __shfl_xor(rsum[rg], m);
        #pragma unroll
        for (int rg = 0; rg < 4; rg++) lrun[rg] += rsum[rg];

        // P -> LDS (wave-local region, same-wave write->read)
        #pragma unroll
        for (int j = 0; j < 4; j++)
            #pragma unroll
            for (int rg = 0; rg < 4; rg++)
                Ps[wave][(lg*4 + rg) * LDT + j*16 + lr] = f32_to_bf16(sv[j][rg]);

        // PV: accO += P @ V
        #pragma unroll
        for (int ksi = 0; ksi < 2; ksi++) {
            bf16x8 ap = *reinterpret_cast<const bf16x8*>(&Ps[wave][lr * LDT + ksi*32 + lg*8]);
            #pragma unroll
            for (int j = 0; j < 4; j++) {
                bf16x8 bv = *reinterpret_cast<const bf16x8*>(&VTs[cur][(j*16 + lr) * LDT + ksi*32 + lg*8]);
                accO[j] = __builtin_amdgcn_mfma_f32_16x16x32_bf16(ap, bv, accO[j], 0, 0, 0);
            }
        }

        if (t + 1 < NT) write_kv(cur ^ 1);  // write late, after compute
        __syncthreads();
    }

    float rinv[4];
    #pragma unroll
    for (int rg = 0; rg < 4; rg++) rinv[rg] = 1.0f / lrun[rg];
    #pragma unroll
    for (int j = 0; j < 4; j++)
        #pragma unroll
        for (int rg = 0; rg < 4; rg++) {
            int srow2 = q0 + wave*16 + lg*4 + rg;
            Aout[((long)(b * Sc + srow2)) * Dc + hh*64 + j*16 + lr] =
                f32_to_bf16(accO[j][rg] * rinv[rg]);
        }
}

extern "C" void kernel_launch(void* const* d_in, const int* in_sizes, int n_in,
                              void* d_out, int out_size, void* d_ws, size_t ws_size,
                              hipStream_t stream) {
    (void)in_sizes; (void)n_in; (void)out_size; (void)ws_size;
    const float* xb = (const float*)d_in[0];
    const int*  mask = (const int*)d_in[1];
    const float* Wq = (const float*)d_in[2];
    const float* bq = (const float*)d_in[3];
    const float* Wk = (const float*)d_in[4];
    const float* bk = (const float*)d_in[5];
    const float* Wv = (const float*)d_in[6];
    const float* bv = (const float*)d_in[7];
    const float* Wo = (const float*)d_in[8];
    const float* bo = (const float*)d_in[9];
    const float* W1 = (const float*)d_in[10];
    const float* b1 = (const float*)d_in[11];
    const float* W2 = (const float*)d_in[12];
    const float* b2 = (const float*)d_in[13];
    const float* a1 = (const float*)d_in[14];
    const float* o1 = (const float*)d_in[15];
    const float* a2 = (const float*)d_in[16];
    const float* o2 = (const float*)d_in[17];
    float* out = (float*)d_out;

    char* p = (char*)d_ws;
    auto alloc = [&](size_t bytes) { char* r = p; p += (bytes + 255) & ~(size_t)255; return r; };
    u16* xln   = (u16*)alloc((size_t)Mc * Dc * 2);
    u16* WTqkv = (u16*)alloc((size_t)3 * Dc * Dc * 2);
    u16* WTo   = (u16*)alloc((size_t)Dc * Dc * 2);
    u16* WT1   = (u16*)alloc((size_t)Dc * DFFc * 2);
    u16* WT2   = (u16*)alloc((size_t)DFFc * Dc * 2);
    u16* qkv   = (u16*)alloc((size_t)3 * Mc * Dc * 2);  // Q | K | VT
    u16* Aat   = (u16*)alloc((size_t)Mc * Dc * 2);
    float* hbuf = (float*)alloc((size_t)Mc * Dc * 4);
    u16* zb  = (u16*)alloc((size_t)Mc * Dc * 2);
    u16* ffh = (u16*)alloc((size_t)Mc * DFFc * 2);

    dim3 blkT(32, 8);
    transpose_conv_kernel<<<dim3(Dc/32,   Dc/32),   blkT, 0, stream>>>(Wq, WTqkv,             Dc, Dc);
    transpose_conv_kernel<<<dim3(Dc/32,   Dc/32),   blkT, 0, stream>>>(Wk, WTqkv + Dc*Dc,     Dc, Dc);
    transpose_conv_kernel<<<dim3(Dc/32,   Dc/32),   blkT, 0, stream>>>(Wv, WTqkv + 2*Dc*Dc,   Dc, Dc);
    transpose_conv_kernel<<<dim3(Dc/32,   Dc/32),   blkT, 0, stream>>>(Wo, WTo, Dc, Dc);
    transpose_conv_kernel<<<dim3(DFFc/32, Dc/32),   blkT, 0, stream>>>(W1, WT1, Dc, DFFc);
    transpose_conv_kernel<<<dim3(Dc/32,   DFFc/32), blkT, 0, stream>>>(W2, WT2, DFFc, Dc);

    ln_kernel<<<Mc, 256, 0, stream>>>(xb, xln, a1, o1);

    // fused Q/K/V projections: z selects weight/bias/output slice
    gemm_kernel<EPI_QKV, 128, 128><<<dim3(Dc/128, Mc/128, 3), 256, 0, stream>>>(
        xln, WTqkv, bq, bk, bv, qkv, nullptr, Mc, Dc, Dc);

    attn_kernel<<<dim3(Sc/128, Bc*Hc), 512, 0, stream>>>(
        qkv, qkv + (size_t)Mc*Dc, qkv + (size_t)2*Mc*Dc, mask, Aat);

    gemm_kernel<EPI_RES, 128, 64><<<dim3(Dc/64, Mc/128), 256, 0, stream>>>(
        Aat, WTo, bo, nullptr, nullptr, hbuf, xb, Mc, Dc, Dc);

    ln_kernel<<<Mc, 256, 0, stream>>>(hbuf, zb, a2, o2);

    gemm_kernel<EPI_RELU, 128, 128><<<dim3(DFFc/128, Mc/128), 256, 0, stream>>>(
        zb, WT1, b1, nullptr, nullptr, ffh, nullptr, Mc, DFFc, Dc);

    gemm_kernel<EPI_RES, 128, 64><<<dim3(Dc/64, Mc/128), 256, 0, stream>>>(
        ffh, WT2, b2, nullptr, nullptr, out, hbuf, Mc, Dc, DFFc);
}

// Round 3
// 306.606 us; speedup vs baseline: 1.2148x; 1.0737x over previous
//
#include <hip/hip_runtime.h>
#include <hip/hip_bf16.h>
#include <math.h>

typedef __bf16 bf16x8 __attribute__((ext_vector_type(8)));
typedef float f32x4 __attribute__((ext_vector_type(4)));
typedef float f32x16 __attribute__((ext_vector_type(16)));
typedef unsigned short u16;

#define DEV __device__ __forceinline__

static constexpr int Bc = 2, Sc = 2048, Dc = 1024, Hc = 16, DFFc = 4096, DKc = 64;
static constexpr int Mc = Bc * Sc; // 4096 rows
static constexpr float QSCALE = 0.125f * 1.4426950408889634f; // fold 1/sqrt(dk) * log2(e) into Q

DEV u16 f32_to_bf16(float x) {
    unsigned u = __builtin_bit_cast(unsigned, x);
    u += 0x7FFFu + ((u >> 16) & 1u);   // round-to-nearest-even
    return (u16)(u >> 16);
}

DEV float exp2_fast(float x) {       // v_exp_f32 computes 2^x natively
    float r;
    asm("v_exp_f32 %0, %1" : "=v"(r) : "v"(x));
    return r;
}

DEV unsigned cvt_pk_bf16(float lo, float hi_) {  // packed f32x2 -> bf16x2 (RTNE)
    unsigned r;
    asm("v_cvt_pk_bf16_f32 %0, %1, %2" : "=v"(r) : "v"(lo), "v"(hi_));
    return r;
}

// async global->LDS, 16B per lane; LDS dest = wave-uniform base + lane*16
DEV void gload_lds16(const u16* g, u16* l) {
    __builtin_amdgcn_global_load_lds(
        (const __attribute__((address_space(1))) void*)g,
        (__attribute__((address_space(3))) void*)l, 16, 0, 0);
}

DEV float block_reduce_sum(float v) {
    __shared__ float part[4];
    int lane = threadIdx.x & 63, w = threadIdx.x >> 6;
    #pragma unroll
    for (int m = 1; m < 64; m <<= 1) v += __shfl_xor(v, m);
    __syncthreads();
    if (lane == 0) part[w] = v;
    __syncthreads();
    return part[0] + part[1] + part[2] + part[3];
}

// LayerNorm over last dim D=1024: f32 in -> bf16 out.
__global__ __launch_bounds__(256)
void ln_kernel(const float* __restrict__ x, u16* __restrict__ y,
               const float* __restrict__ alpha, const float* __restrict__ beta) {
    long row = blockIdx.x;
    const float4 v = reinterpret_cast<const float4*>(x + row * Dc)[threadIdx.x];
    float s = v.x + v.y + v.z + v.w;
    s = block_reduce_sum(s);
    float mean = s * (1.0f / Dc);
    float d0 = v.x - mean, d1 = v.y - mean, d2 = v.z - mean, d3 = v.w - mean;
    float ss = d0*d0 + d1*d1 + d2*d2 + d3*d3;
    ss = block_reduce_sum(ss);
    float stdv = sqrtf(ss / (float)(Dc - 1));
    float sc = alpha[0] / (stdv + 1e-6f);
    float bi = beta[0];
    ushort4 o;
    o.x = f32_to_bf16(d0 * sc + bi);
    o.y = f32_to_bf16(d1 * sc + bi);
    o.z = f32_to_bf16(d2 * sc + bi);
    o.w = f32_to_bf16(d3 * sc + bi);
    reinterpret_cast<ushort4*>(y + row * Dc)[threadIdx.x] = o;
}

// f32 W[K][N] -> bf16 WT[N][K]
__global__ void transpose_conv_kernel(const float* __restrict__ in, u16* __restrict__ out,
                                      int K, int N) {
    __shared__ float tile[32][33];
    int k0 = blockIdx.y * 32, n0 = blockIdx.x * 32;
    int tx = threadIdx.x, ty = threadIdx.y; // (32,8)
    #pragma unroll
    for (int i = 0; i < 4; i++)
        tile[ty + i*8][tx] = in[(long)(k0 + ty + i*8) * N + n0 + tx];
    __syncthreads();
    #pragma unroll
    for (int i = 0; i < 4; i++)
        out[(long)(n0 + ty + i*8) * K + k0 + tx] = f32_to_bf16(tile[tx][ty + i*8]);
}

// ---------------- bf16 GEMM (m97 structure): C = A[M,K] @ B with B as BT[N][K] ----------------
enum { EPI_QKV = 0, EPI_RELU = 1, EPI_RES = 2 };

template<int EPI, int BM, int BN>
__global__ __launch_bounds__(256, 3)
void gemm_kernel(const u16* __restrict__ A, const u16* __restrict__ BT,
                 const float* __restrict__ b0, const float* __restrict__ b1,
                 const float* __restrict__ b2, void* __restrict__ outp,
                 const float* __restrict__ res, int M, int N, int K) {
    constexpr int BK = 64, RI = BM / 32, RJ = BN / 32;
    __shared__ u16 As[BM * BK];
    __shared__ u16 Bs[BN * BK];
    const int tid = threadIdx.x;
    const int wave = tid >> 6, lane = tid & 63;
    const int wr = wave >> 1, wc = wave & 1;
    const int lr = lane & 15, lg = lane >> 4;
    const int m0 = blockIdx.y * BM, n0 = blockIdx.x * BN;
    const int z = blockIdx.z;
    const u16* Bz = BT + (size_t)z * N * K;
    const int srow = lane >> 3, scol = (lane & 7) * 8;

    f32x4 acc[RI][RJ] = {};

    const u16* ap[RI];
    const u16* bp[RJ];
    #pragma unroll
    for (int i = 0; i < RI; i++) ap[i] = A  + (size_t)(m0 + (wave*RI + i)*8 + srow) * K + scol;
    #pragma unroll
    for (int j = 0; j < RJ; j++) bp[j] = Bz + (size_t)(n0 + (wave*RJ + j)*8 + srow) * K + scol;

    for (int kt = 0; kt < K; kt += BK) {
        #pragma unroll
        for (int i = 0; i < RI; i++) gload_lds16(ap[i] + kt, &As[(wave*RI + i) * 512]);
        #pragma unroll
        for (int j = 0; j < RJ; j++) gload_lds16(bp[j] + kt, &Bs[(wave*RJ + j) * 512]);
        __syncthreads();
        #pragma unroll
        for (int ks = 0; ks < BK; ks += 32) {
            bf16x8 a[RI], b[RJ];
            #pragma unroll
            for (int i = 0; i < RI; i++)
                a[i] = *reinterpret_cast<const bf16x8*>(&As[(wr*(BM/2) + i*16 + lr) * BK + ks + lg*8]);
            #pragma unroll
            for (int j = 0; j < RJ; j++)
                b[j] = *reinterpret_cast<const bf16x8*>(&Bs[(wc*(BN/2) + j*16 + lr) * BK + ks + lg*8]);
            #pragma unroll
            for (int i = 0; i < RI; i++)
                #pragma unroll
                for (int j = 0; j < RJ; j++)
                    acc[i][j] = __builtin_amdgcn_mfma_f32_16x16x32_bf16(a[i], b[j], acc[i][j], 0, 0, 0);
        }
        __syncthreads();
    }

    const float* bias = (EPI == EPI_QKV) ? (z == 0 ? b0 : z == 1 ? b1 : b2) : b0;
    #pragma unroll
    for (int i = 0; i < RI; i++) {
        #pragma unroll
        for (int j = 0; j < RJ; j++) {
            const int col = n0 + wc*(BN/2) + j*16 + lr;
            const float bv = bias[col];
            #pragma unroll
            for (int rg = 0; rg < 4; rg++) {
                const int row = m0 + wr*(BM/2) + i*16 + lg*4 + rg;
                float val = acc[i][j][rg] + bv;
                if constexpr (EPI == EPI_QKV) {
                    int bb = row >> 11, s = row & (Sc - 1);
                    int hh = col >> 6, dk = col & 63;
                    u16* o = (u16*)outp + (size_t)z * Mc * Dc;
                    if (z == 2)  // V transposed: [B,H,DK,S]
                        o[((size_t)(bb * Hc + hh) * DKc + dk) * Sc + s] = f32_to_bf16(val);
                    else         // Q (pre-scaled, log2 domain) / K: [B,H,S,DK]
                        o[(((size_t)(bb * Hc + hh) * Sc + s) << 6) + dk] =
                            f32_to_bf16(z == 0 ? val * QSCALE : val);
                } else if constexpr (EPI == EPI_RELU) {
                    ((u16*)outp)[(size_t)row * N + col] = f32_to_bf16(fmaxf(val, 0.0f));
                } else { // EPI_RES: out(f32) = res + acc + bias
                    size_t idx = (size_t)row * N + col;
                    ((float*)outp)[idx] = res[idx] + val;
                }
            }
        }
    }
}

// ---------------- flash attention, swapped-QK^T 32x32 (m214-style) ----------------
// grid (S/128, B*H), 256 threads (4 waves), each wave owns 32 q-rows.
// Q,K: [B,H,S,64] bf16 (Q pre-scaled by 1/8*log2e). VT: [B,H,64,S]. out: [B,S,D] bf16.
// S^T = mfma(K,Q): lane holds a full q-row (q = lane&31) -> in-lane softmax.
// K/V LDS tiles XOR-swizzled (16B slot ^= row&7) -> conflict-free ds_read_b128.
__global__ __launch_bounds__(256)
void attn_kernel(const u16* __restrict__ Qg, const u16* __restrict__ Kg,
                 const u16* __restrict__ VTg, const int* __restrict__ mask,
                 u16* __restrict__ Aout) {
    constexpr int KVB = 64, NT = Sc / KVB;
    __shared__ u16 Ks[2][KVB * DKc];   // [k][dk], swizzled
    __shared__ u16 VTs[2][DKc * KVB];  // [d][s],  swizzled
    __shared__ float mb_full[Sc];

    const int tid = threadIdx.x;
    const int wave = tid >> 6, lane = tid & 63;
    const int l31 = lane & 31, hi = lane >> 5;
    const int bh = blockIdx.y, b = bh >> 4, hh = bh & 15;
    const int q0 = blockIdx.x * 128 + wave * 32;
    const long base = (long)bh * Sc * DKc;

    for (int i = tid; i < Sc; i += 256)
        mb_full[i] = mask[b * Sc + i] ? 0.f : -1e9f;

    // Q fragments (B-operand): row q = l31, kdim = step*16 + hi*8
    bf16x8 qf[4];
    {
        const u16* qrow = Qg + base + (long)(q0 + l31) * DKc + hi * 8;
        #pragma unroll
        for (int s = 0; s < 4; s++)
            qf[s] = *reinterpret_cast<const bf16x8*>(qrow + s * 16);
    }

    uint4 kreg[2], vreg[2];
    auto load_kv = [&](int kt) {
        #pragma unroll
        for (int i = 0; i < 2; i++) {
            int c = tid + i * 256, r = c >> 3, sl = (c & 7) * 8;
            kreg[i] = *reinterpret_cast<const uint4*>(&Kg [base + (long)(kt + r) * DKc + sl]);
            vreg[i] = *reinterpret_cast<const uint4*>(&VTg[base + (long)r * Sc + kt + sl]);
        }
    };
    auto write_kv = [&](int bi) {
        #pragma unroll
        for (int i = 0; i < 2; i++) {
            int c = tid + i * 256, r = c >> 3, sl = c & 7;
            int ws = (sl ^ (r & 7)) * 8;
            *reinterpret_cast<uint4*>(&Ks [bi][r * DKc + ws]) = kreg[i];
            *reinterpret_cast<uint4*>(&VTs[bi][r * KVB + ws]) = vreg[i];
        }
    };

    load_kv(0); write_kv(0);
    __syncthreads();
    load_kv(KVB);   // NT >= 2 always here

    f32x16 accO[2] = {};            // dt: d = dt*32 + l31; reg r: q = (r&3)+8*(r>>2)+4*hi
    float mrun = -3.0e38f, lrun = 0.f;

    for (int t = 0; t < NT; t++) {
        const int cur = t & 1;
        if (t + 1 < NT) write_kv(cur ^ 1);      // data for t+1 (loaded last iter)
        if (t + 2 < NT) load_kv((t + 2) * KVB); // issue early (T14)

        // S^T = K Q^T : st[kt2][r] = S[k = kt2*32 + qr(r,hi)][q = l31]
        f32x16 st[2];
        #pragma unroll
        for (int kt2 = 0; kt2 < 2; kt2++) {
            f32x16 s = {};
            const int row = kt2 * 32 + l31;
            #pragma unroll
            for (int step = 0; step < 4; step++) {
                const int unit = (step * 2 + hi) ^ (row & 7);
                bf16x8 kf = *reinterpret_cast<const bf16x8*>(&Ks[cur][row * DKc + unit * 8]);
                s = __builtin_amdgcn_mfma_f32_32x32x16_bf16(kf, qf[step], s, 0, 0, 0);
            }
            st[kt2] = s;
        }

        // mask add + in-lane row max (32 vals/lane, all same q-row)
        float pm = -3.0e38f;
        #pragma unroll
        for (int kt2 = 0; kt2 < 2; kt2++) {
            #pragma unroll
            for (int g = 0; g < 4; g++) {
                const float4 mb = *reinterpret_cast<const float4*>(
                    &mb_full[t * KVB + kt2 * 32 + g * 8 + hi * 4]);
                st[kt2][g*4+0] += mb.x;
                st[kt2][g*4+1] += mb.y;
                st[kt2][g*4+2] += mb.z;
                st[kt2][g*4+3] += mb.w;
                pm = fmaxf(pm, fmaxf(fmaxf(st[kt2][g*4+0], st[kt2][g*4+1]),
                                     fmaxf(st[kt2][g*4+2], st[kt2][g*4+3])));
            }
        }
        pm = fmaxf(pm, __shfl_xor(pm, 32));   // combine k-halves (same q-row)

        // defer-rescale (T13): threshold 8 nats = 11.54 in log2 domain
        if (__any(pm - mrun > 11.54f)) {
            const float mnew = fmaxf(mrun, pm);
            const float corr = exp2_fast(mrun - mnew);
            mrun = mnew; lrun *= corr;
            #pragma unroll
            for (int r = 0; r < 16; r++) {
                const int qr = (r & 3) + 8 * (r >> 2) + 4 * hi;
                const float cr = __builtin_bit_cast(float,
                    __builtin_amdgcn_ds_bpermute(qr << 2, __builtin_bit_cast(int, corr)));
                accO[0][r] *= cr;
                accO[1][r] *= cr;
            }
        }

        // exp2 + in-lane sum
        float rsum = 0.f;
        #pragma unroll
        for (int kt2 = 0; kt2 < 2; kt2++)
            #pragma unroll
            for (int r = 0; r < 16; r++) {
                const float p = exp2_fast(st[kt2][r] - mrun);
                st[kt2][r] = p;
                rsum += p;
            }
        rsum += __shfl_xor(rsum, 32);
        lrun += rsum;

        // P -> bf16 A-fragments (in-register, T12 via shfl_xor(32)) and PV
        #pragma unroll
        for (int kt2 = 0; kt2 < 2; kt2++) {
            #pragma unroll
            for (int kstep = 0; kstep < 2; kstep++) {
                unsigned w0 = cvt_pk_bf16(st[kt2][kstep*8+0], st[kt2][kstep*8+1]);
                unsigned w1 = cvt_pk_bf16(st[kt2][kstep*8+2], st[kt2][kstep*8+3]);
                unsigned w2 = cvt_pk_bf16(st[kt2][kstep*8+4], st[kt2][kstep*8+5]);
                unsigned w3 = cvt_pk_bf16(st[kt2][kstep*8+6], st[kt2][kstep*8+7]);
                const unsigned p0 = (unsigned)__shfl_xor((int)w0, 32);
                const unsigned p1 = (unsigned)__shfl_xor((int)w1, 32);
                const unsigned p2 = (unsigned)__shfl_xor((int)w2, 32);
                const unsigned p3 = (unsigned)__shfl_xor((int)w3, 32);
                uint4 e;
                e.x = hi ? p2 : w0;   // k-elems 0,1 of this lane's frag
                e.y = hi ? p3 : w1;   // 2,3
                e.z = hi ? w2 : p0;   // 4,5
                e.w = hi ? w3 : p1;   // 6,7
                const bf16x8 pa = __builtin_bit_cast(bf16x8, e);
                #pragma unroll
                for (int dt = 0; dt < 2; dt++) {
                    const int drow = dt * 32 + l31;
                    const int unit = (kt2 * 4 + kstep * 2 + hi) ^ (drow & 7);
                    bf16x8 vf = *reinterpret_cast<const bf16x8*>(&VTs[cur][drow * KVB + unit * 8]);
                    accO[dt] = __builtin_amdgcn_mfma_f32_32x32x16_bf16(pa, vf, accO[dt], 0, 0, 0);
                }
            }
        }
        __syncthreads();
    }

    // epilogue: per-q normalization (q varies per acc reg -> bpermute 1/lrun)
    const float rinv = 1.0f / lrun;
    #pragma unroll
    for (int r = 0; r < 16; r++) {
        const int qr = (r & 3) + 8 * (r >> 2) + 4 * hi;
        const float rv = __builtin_bit_cast(float,
            __builtin_amdgcn_ds_bpermute(qr << 2, __builtin_bit_cast(int, rinv)));
        const int srow = q0 + qr;
        #pragma unroll
        for (int dt = 0; dt < 2; dt++)
            Aout[((long)(b * Sc + srow)) * Dc + hh*64 + dt*32 + l31] =
                f32_to_bf16(accO[dt][r] * rv);
    }
}

extern "C" void kernel_launch(void* const* d_in, const int* in_sizes, int n_in,
                              void* d_out, int out_size, void* d_ws, size_t ws_size,
                              hipStream_t stream) {
    (void)in_sizes; (void)n_in; (void)out_size; (void)ws_size;
    const float* xb = (const float*)d_in[0];
    const int*  mask = (const int*)d_in[1];
    const float* Wq = (const float*)d_in[2];
    const float* bq = (const float*)d_in[3];
    const float* Wk = (const float*)d_in[4];
    const float* bk = (const float*)d_in[5];
    const float* Wv = (const float*)d_in[6];
    const float* bv = (const float*)d_in[7];
    const float* Wo = (const float*)d_in[8];
    const float* bo = (const float*)d_in[9];
    const float* W1 = (const float*)d_in[10];
    const float* b1 = (const float*)d_in[11];
    const float* W2 = (const float*)d_in[12];
    const float* b2 = (const float*)d_in[13];
    const float* a1 = (const float*)d_in[14];
    const float* o1 = (const float*)d_in[15];
    const float* a2 = (const float*)d_in[16];
    const float* o2 = (const float*)d_in[17];
    float* out = (float*)d_out;

    char* p = (char*)d_ws;
    auto alloc = [&](size_t bytes) { char* r = p; p += (bytes + 255) & ~(size_t)255; return r; };
    u16* xln   = (u16*)alloc((size_t)Mc * Dc * 2);
    u16* WTqkv = (u16*)alloc((size_t)3 * Dc * Dc * 2);
    u16* WTo   = (u16*)alloc((size_t)Dc * Dc * 2);
    u16* WT1   = (u16*)alloc((size_t)Dc * DFFc * 2);
    u16* WT2   = (u16*)alloc((size_t)DFFc * Dc * 2);
    u16* qkv   = (u16*)alloc((size_t)3 * Mc * Dc * 2);  // Q | K | VT
    u16* Aat   = (u16*)alloc((size_t)Mc * Dc * 2);
    float* hbuf = (float*)alloc((size_t)Mc * Dc * 4);
    u16* zb  = (u16*)alloc((size_t)Mc * Dc * 2);
    u16* ffh = (u16*)alloc((size_t)Mc * DFFc * 2);

    dim3 blkT(32, 8);
    transpose_conv_kernel<<<dim3(Dc/32,   Dc/32),   blkT, 0, stream>>>(Wq, WTqkv,             Dc, Dc);
    transpose_conv_kernel<<<dim3(Dc/32,   Dc/32),   blkT, 0, stream>>>(Wk, WTqkv + Dc*Dc,     Dc, Dc);
    transpose_conv_kernel<<<dim3(Dc/32,   Dc/32),   blkT, 0, stream>>>(Wv, WTqkv + 2*Dc*Dc,   Dc, Dc);
    transpose_conv_kernel<<<dim3(Dc/32,   Dc/32),   blkT, 0, stream>>>(Wo, WTo, Dc, Dc);
    transpose_conv_kernel<<<dim3(DFFc/32, Dc/32),   blkT, 0, stream>>>(W1, WT1, Dc, DFFc);
    transpose_conv_kernel<<<dim3(Dc/32,   DFFc/32), blkT, 0, stream>>>(W2, WT2, DFFc, Dc);

    ln_kernel<<<Mc, 256, 0, stream>>>(xb, xln, a1, o1);

    gemm_kernel<EPI_QKV, 128, 128><<<dim3(Dc/128, Mc/128, 3), 256, 0, stream>>>(
        xln, WTqkv, bq, bk, bv, qkv, nullptr, Mc, Dc, Dc);

    attn_kernel<<<dim3(Sc/128, Bc*Hc), 256, 0, stream>>>(
        qkv, qkv + (size_t)Mc*Dc, qkv + (size_t)2*Mc*Dc, mask, Aat);

    gemm_kernel<EPI_RES, 128, 64><<<dim3(Dc/64, Mc/128), 256, 0, stream>>>(
        Aat, WTo, bo, nullptr, nullptr, hbuf, xb, Mc, Dc, Dc);

    ln_kernel<<<Mc, 256, 0, stream>>>(hbuf, zb, a2, o2);

    gemm_kernel<EPI_RELU, 128, 128><<<dim3(DFFc/128, Mc/128), 256, 0, stream>>>(
        zb, WT1, b1, nullptr, nullptr, ffh, nullptr, Mc, DFFc, Dc);

    gemm_kernel<EPI_RES, 128, 64><<<dim3(Dc/64, Mc/128), 256, 0, stream>>>(
        ffh, WT2, b2, nullptr, nullptr, out, hbuf, Mc, Dc, DFFc);
}